// Round 7
// baseline (234.751 us; speedup 1.0000x reference)
//
#include <hip/hip_runtime.h>
#include <math.h>

#define NB   1024
#define NACT 256
#define DIM  256
#define HDIM 512
#define ADIM 512
#define KTOT 1024
#define NE   100000
#define NR   400
#define NRP  448            // NR padded to 64
#define G1B  128            // gemm1 blocks (first in mega grid)

typedef __attribute__((ext_vector_type(8))) short bf16x8;
typedef __attribute__((ext_vector_type(4))) float f32x4;

__device__ __forceinline__ unsigned short f2bf(float f) {
    unsigned int u = __float_as_uint(f);
    u += 0x7FFF + ((u >> 16) & 1);
    return (unsigned short)(u >> 16);
}
__device__ __forceinline__ float bf2f(unsigned short u) {
    return __uint_as_float(((unsigned int)u) << 16);
}
__device__ __forceinline__ ushort4 cvt4(float4 v) {
    ushort4 o = {f2bf(v.x), f2bf(v.y), f2bf(v.z), f2bf(v.w)};
    return o;
}

// ---------------- prep_transpose: W[K][N] fp32 -> WT[N][K] bf16 ----------------
__global__ __launch_bounds__(256) void prep_transpose(
    const float* __restrict__ W1, const float* __restrict__ W2,
    ushort* __restrict__ W1T, ushort* __restrict__ W2T)
{
    __shared__ float t[64][68];
    const int z = blockIdx.z;
    if (z && blockIdx.x >= 8) return;                 // W2 has K=512
    const int Kd = z ? 512 : 1024;
    const float* in = z ? W2 : W1;
    ushort* out = z ? W2T : W1T;
    const int k0 = blockIdx.x * 64, n0 = blockIdx.y * 64;
    const int tid = threadIdx.x;
    const int kr = tid >> 2, c = tid & 3;
    #pragma unroll
    for (int j = 0; j < 4; ++j) {
        const float4 v = *(const float4*)(in + (size_t)(k0 + kr) * ADIM + n0 + c * 16 + j * 4);
        *(float4*)&t[kr][c * 16 + j * 4] = v;
    }
    __syncthreads();
    const int nr = tid >> 2;
    ushort tmp[16];
    #pragma unroll
    for (int kk = 0; kk < 16; ++kk) tmp[kk] = f2bf(t[c * 16 + kk][nr]);
    *(uint4*)(out + (size_t)(n0 + nr) * Kd + k0 + c * 16)     = *(uint4*)&tmp[0];
    *(uint4*)(out + (size_t)(n0 + nr) * Kd + k0 + c * 16 + 8) = *(uint4*)&tmp[8];
}

// ---------------- mega: blocks [0,128) gemm1 MFMA; [128,1152) table conversion ----------------
__global__ __launch_bounds__(256) void mega_conv_gemm1(
    const float* __restrict__ ent, const float* __restrict__ rel,
    const float* __restrict__ hstate,
    const int* __restrict__ e, const int* __restrict__ q,
    const ushort* __restrict__ W1T, const float* __restrict__ b1,
    ushort* __restrict__ entbf, ushort* __restrict__ relbf,
    ushort* __restrict__ Hbf)
{
    const int blk = blockIdx.x, tid = threadIdx.x;
    __shared__ __align__(16) ushort Als[64][40];   // 32 k + 8 pad -> 80 B rows
    __shared__ __align__(16) ushort Bls[64][40];

    if (blk >= G1B) {
        // ---- streaming fp32 -> bf16 conversion, 4 loads in flight ----
        const int cb = blk - G1B;                     // 0..1023
        const float4* src = (const float4*)ent;
        ushort4* dst = (ushort4*)entbf;
        const int start = cb * 6250;                  // 1024*6250 = NE*DIM/4
        const int end = start + 6250;
        int j = start + tid;
        for (; j + 768 < end; j += 1024) {
            const float4 v0 = src[j];
            const float4 v1 = src[j + 256];
            const float4 v2 = src[j + 512];
            const float4 v3 = src[j + 768];
            dst[j]       = cvt4(v0);
            dst[j + 256] = cvt4(v1);
            dst[j + 512] = cvt4(v2);
            dst[j + 768] = cvt4(v3);
        }
        for (; j < end; j += 256) dst[j] = cvt4(src[j]);
        if (cb < 100) {                               // rel: 25600 float4
            const int k = cb * 256 + tid;
            ((ushort4*)relbf)[k] = cvt4(((const float4*)rel)[k]);
        }
        return;
    }

    // ---- gemm1: Hbf = relu_bf16(gather[E|H|Q] @ W1T^T + b1) ----
    const int g  = blk;                               // 0..127
    const int n0 = (g & 7) * 64;
    const int m0 = (g >> 3) * 64;
    const int wave = tid >> 6, lane = tid & 63;
    const int qq   = lane >> 4, l15 = lane & 15;
    const int sm   = tid >> 2, sc = tid & 3;
    const int kofs = sc * 8;

    const int row   = m0 + sm;
    const float* rowE = ent + (size_t)e[row] * DIM;
    const float* rowH = hstate + (size_t)row * HDIM - DIM;
    const float* rowQ = rel + (size_t)q[row] * DIM - (DIM + HDIM);
    const uint4* gb = (const uint4*)(W1T + (size_t)(n0 + sm) * KTOT) + sc;

    f32x4 acc[4];
    #pragma unroll
    for (int mt = 0; mt < 4; ++mt) acc[mt] = (f32x4){0.f, 0.f, 0.f, 0.f};

    float4 pa0 = *(const float4*)(rowE + kofs);
    float4 pa1 = *(const float4*)(rowE + kofs + 4);
    uint4  pb  = gb[0];

    for (int it = 0; it < KTOT / 32; ++it) {
        ushort t8[8];
        t8[0] = f2bf(pa0.x); t8[1] = f2bf(pa0.y); t8[2] = f2bf(pa0.z); t8[3] = f2bf(pa0.w);
        t8[4] = f2bf(pa1.x); t8[5] = f2bf(pa1.y); t8[6] = f2bf(pa1.z); t8[7] = f2bf(pa1.w);
        *(uint4*)&Als[sm][sc * 8] = *(uint4*)t8;
        *(uint4*)&Bls[sm][sc * 8] = pb;
        __syncthreads();
        if (it + 1 < KTOT / 32) {
            const int kg = (it + 1) * 32 + kofs;
            const float* src = (kg < DIM) ? rowE : ((kg < DIM + HDIM) ? rowH : rowQ);
            pa0 = *(const float4*)(src + kg);
            pa1 = *(const float4*)(src + kg + 4);
            pb  = gb[(it + 1) * 4];
        }
        const bf16x8 bfrag = *(const bf16x8*)&Bls[wave * 16 + l15][qq * 8];
        #pragma unroll
        for (int mt = 0; mt < 4; ++mt) {
            const bf16x8 afrag = *(const bf16x8*)&Als[mt * 16 + l15][qq * 8];
            acc[mt] = __builtin_amdgcn_mfma_f32_16x16x32_bf16(afrag, bfrag, acc[mt], 0, 0, 0);
        }
        __syncthreads();
    }
    const int n = n0 + wave * 16 + l15;
    const float bv = b1[n];
    #pragma unroll
    for (int mt = 0; mt < 4; ++mt)
        #pragma unroll
        for (int r = 0; r < 4; ++r) {
            const int m = m0 + mt * 16 + qq * 4 + r;
            Hbf[(size_t)m * ADIM + n] = f2bf(fmaxf(acc[mt][r] + bv, 0.0f));
        }
}

// ---------------- gemm2 MFMA: X2 = Hbf @ W2T^T + b2; also bf16 copy of cols<256 ----------------
__global__ __launch_bounds__(256) void gemm2_mfma(
    const ushort* __restrict__ A, const ushort* __restrict__ Bt,
    const float* __restrict__ bias, float* __restrict__ Cf,
    ushort* __restrict__ X2rbf)
{
    __shared__ __align__(16) ushort Als[64][40];
    __shared__ __align__(16) ushort Bls[64][40];
    const int tid  = threadIdx.x;
    const int n0   = blockIdx.x * 64;
    const int m0   = blockIdx.y * 64;
    const int wave = tid >> 6, lane = tid & 63;
    const int qq   = lane >> 4, l15 = lane & 15;
    const int sm   = tid >> 2, sc = tid & 3;

    const uint4* ga = (const uint4*)(A  + (size_t)(m0 + sm) * ADIM) + sc;
    const uint4* gb = (const uint4*)(Bt + (size_t)(n0 + sm) * ADIM) + sc;

    f32x4 acc[4];
    #pragma unroll
    for (int mt = 0; mt < 4; ++mt) acc[mt] = (f32x4){0.f, 0.f, 0.f, 0.f};

    uint4 pa = ga[0], pb = gb[0];
    for (int it = 0; it < ADIM / 32; ++it) {
        *(uint4*)&Als[sm][sc * 8] = pa;
        *(uint4*)&Bls[sm][sc * 8] = pb;
        __syncthreads();
        if (it + 1 < ADIM / 32) {
            pa = ga[(it + 1) * 4];
            pb = gb[(it + 1) * 4];
        }
        const bf16x8 bfrag = *(const bf16x8*)&Bls[wave * 16 + l15][qq * 8];
        #pragma unroll
        for (int mt = 0; mt < 4; ++mt) {
            const bf16x8 afrag = *(const bf16x8*)&Als[mt * 16 + l15][qq * 8];
            acc[mt] = __builtin_amdgcn_mfma_f32_16x16x32_bf16(afrag, bfrag, acc[mt], 0, 0, 0);
        }
        __syncthreads();
    }
    const int n = n0 + wave * 16 + l15;
    const float bv = bias[n];
    const bool lowhalf = (n0 < 256);
    #pragma unroll
    for (int mt = 0; mt < 4; ++mt)
        #pragma unroll
        for (int r = 0; r < 4; ++r) {
            const int m = m0 + mt * 16 + qq * 4 + r;
            const float v = acc[mt][r] + bv;
            Cf[(size_t)m * ADIM + n] = v;
            if (lowhalf) X2rbf[(size_t)m * DIM + n] = f2bf(v);
        }
}

// ---------------- gemm_rel: R[b][j] = X2rbf[b,:] . relbf[j,:]  (fp32 out, N=400 pad 448) ----------------
__global__ __launch_bounds__(256) void gemm_rel(
    const ushort* __restrict__ A, const ushort* __restrict__ Bt,
    float* __restrict__ R)
{
    __shared__ __align__(16) ushort Als[64][40];
    __shared__ __align__(16) ushort Bls[64][40];
    const int tid  = threadIdx.x;
    const int n0   = blockIdx.x * 64;
    const int m0   = blockIdx.y * 64;
    const int wave = tid >> 6, lane = tid & 63;
    const int qq   = lane >> 4, l15 = lane & 15;
    const int sm   = tid >> 2, sc = tid & 3;

    const int brow = (n0 + sm < NR) ? (n0 + sm) : (NR - 1);
    const uint4* ga = (const uint4*)(A  + (size_t)(m0 + sm) * DIM) + sc;
    const uint4* gb = (const uint4*)(Bt + (size_t)brow * DIM) + sc;

    f32x4 acc[4];
    #pragma unroll
    for (int mt = 0; mt < 4; ++mt) acc[mt] = (f32x4){0.f, 0.f, 0.f, 0.f};

    uint4 pa = ga[0], pb = gb[0];
    for (int it = 0; it < DIM / 32; ++it) {
        *(uint4*)&Als[sm][sc * 8] = pa;
        *(uint4*)&Bls[sm][sc * 8] = pb;
        __syncthreads();
        if (it + 1 < DIM / 32) {
            pa = ga[(it + 1) * 4];
            pb = gb[(it + 1) * 4];
        }
        const bf16x8 bfrag = *(const bf16x8*)&Bls[wave * 16 + l15][qq * 8];
        #pragma unroll
        for (int mt = 0; mt < 4; ++mt) {
            const bf16x8 afrag = *(const bf16x8*)&Als[mt * 16 + l15][qq * 8];
            acc[mt] = __builtin_amdgcn_mfma_f32_16x16x32_bf16(afrag, bfrag, acc[mt], 0, 0, 0);
        }
        __syncthreads();
    }
    const int n = n0 + wave * 16 + l15;
    if (n < NR) {
        #pragma unroll
        for (int mt = 0; mt < 4; ++mt)
            #pragma unroll
            for (int r = 0; r < 4; ++r) {
                const int m = m0 + mt * 16 + qq * 4 + r;
                R[(size_t)m * NRP + n] = acc[mt][r];
            }
    }
}

// ------------- scores: ent gather + R lookup + masked softmax + entropy -------------
__global__ __launch_bounds__(512) void scores_kernel(
    const int* __restrict__ r_space, const int* __restrict__ e_space,
    const float* __restrict__ amask,
    const ushort* __restrict__ entbf, const float* __restrict__ R,
    const float* __restrict__ X2,
    float* __restrict__ dist_out, float* __restrict__ ent_out)
{
    const int b    = blockIdx.x;
    const int tid  = threadIdx.x;
    const int wave = tid >> 6;
    const int lane = tid & 63;

    __shared__ float xs[ADIM];
    __shared__ float sc[NACT];
    __shared__ int   ridx[NACT];
    __shared__ int   eidx[NACT];
    __shared__ float red1[8], red2[8], red3[8];

    if (tid < NACT) ridx[tid] = r_space[(size_t)b * NACT + tid];
    else            eidx[tid - NACT] = e_space[(size_t)b * NACT + tid - NACT];
    if (tid < ADIM / 4)
        ((float4*)xs)[tid] = ((const float4*)(X2 + (size_t)b * ADIM))[tid];
    __syncthreads();

    const float4 xe = ((const float4*)(xs + DIM))[lane];
    const float* R_row = R + (size_t)b * NRP;

    const int abase = wave * 32;
    for (int a0 = abase; a0 < abase + 32; a0 += 16) {
        // prefetch the rel partial for the action this lane will publish
        const float rsc = (lane < 16) ? R_row[ridx[a0 + lane]] : 0.0f;
        ushort4 ev[16];
        #pragma unroll
        for (int i = 0; i < 16; ++i)
            ev[i] = ((const ushort4*)entbf)[(size_t)eidx[a0 + i] * (DIM / 4) + lane];
        float p[16];
        #pragma unroll
        for (int i = 0; i < 16; ++i) {
            p[i] = bf2f(ev[i].x) * xe.x + bf2f(ev[i].y) * xe.y
                 + bf2f(ev[i].z) * xe.z + bf2f(ev[i].w) * xe.w;
        }
        #pragma unroll
        for (int off = 32; off; off >>= 1) {
            #pragma unroll
            for (int i = 0; i < 16; ++i) p[i] += __shfl_xor(p[i], off);
        }
        float out = p[0];
        #pragma unroll
        for (int i = 1; i < 16; ++i) out = (lane == i) ? p[i] : out;
        if (lane < 16) sc[a0 + lane] = out + rsc;
    }
    __syncthreads();

    float s = -3.0e38f;
    if (tid < NACT) {
        const float m = amask[(size_t)b * NACT + tid];
        s = sc[tid] - (1.0f - m) * 1e31f;
    }

    float mx = s;
    #pragma unroll
    for (int off = 32; off; off >>= 1) mx = fmaxf(mx, __shfl_xor(mx, off));
    if (lane == 0) red1[wave] = mx;
    __syncthreads();
    mx = red1[0];
    #pragma unroll
    for (int w = 1; w < 8; ++w) mx = fmaxf(mx, red1[w]);

    const float ex = (tid < NACT) ? expf(s - mx) : 0.0f;
    float sum = ex;
    #pragma unroll
    for (int off = 32; off; off >>= 1) sum += __shfl_xor(sum, off);
    if (lane == 0) red2[wave] = sum;
    __syncthreads();
    sum = ((red2[0] + red2[1]) + (red2[2] + red2[3]))
        + ((red2[4] + red2[5]) + (red2[6] + red2[7]));

    const float d = ex / sum;
    if (tid < NACT) dist_out[(size_t)b * NACT + tid] = d;

    float t = (tid < NACT) ? d * logf(fmaxf(d, 1e-20f)) : 0.0f;
    #pragma unroll
    for (int off = 32; off; off >>= 1) t += __shfl_xor(t, off);
    if (lane == 0) red3[wave] = t;
    __syncthreads();
    if (tid == 0)
        ent_out[b] = -(((red3[0] + red3[1]) + (red3[2] + red3[3]))
                     + ((red3[4] + red3[5]) + (red3[6] + red3[7])));
}

extern "C" void kernel_launch(void* const* d_in, const int* in_sizes, int n_in,
                              void* d_out, int out_size, void* d_ws, size_t ws_size,
                              hipStream_t stream) {
    const int*   e       = (const int*)d_in[0];
    const int*   q       = (const int*)d_in[1];
    const float* hstate  = (const float*)d_in[2];
    const int*   r_space = (const int*)d_in[3];
    const int*   e_space = (const int*)d_in[4];
    const float* amask   = (const float*)d_in[5];
    const float* ent     = (const float*)d_in[6];
    const float* rel     = (const float*)d_in[7];
    const float* W1      = (const float*)d_in[8];
    const float* b1      = (const float*)d_in[9];
    const float* W2      = (const float*)d_in[10];
    const float* b2      = (const float*)d_in[11];

    ushort* W1T   = (ushort*)d_ws;                       // 512*1024
    ushort* W2T   = W1T   + (size_t)ADIM * KTOT;         // 512*512
    ushort* Hbf   = W2T   + (size_t)ADIM * ADIM;         // 1024*512
    ushort* entbf = Hbf   + (size_t)NB * ADIM;           // 100000*256
    ushort* relbf = entbf + (size_t)NE * DIM;            // 400*256
    float*  X2    = (float*)(relbf + (size_t)NR * DIM);  // 1024*512 f32
    ushort* X2rbf = (ushort*)(X2 + (size_t)NB * ADIM);   // 1024*256
    float*  Rtab  = (float*)(X2rbf + (size_t)NB * DIM);  // 1024*448 f32
    float*  dist  = (float*)d_out;
    float*  entr  = dist + (size_t)NB * NACT;

    prep_transpose<<<dim3(16, 8, 2), 256, 0, stream>>>(W1, W2, W1T, W2T);
    mega_conv_gemm1<<<G1B + 1024, 256, 0, stream>>>(
        ent, rel, hstate, e, q, W1T, b1, entbf, relbf, Hbf);
    gemm2_mfma<<<dim3(ADIM / 64, NB / 64), 256, 0, stream>>>(Hbf, W2T, b2, X2, X2rbf);
    gemm_rel<<<dim3(NRP / 64, NB / 64), 256, 0, stream>>>(X2rbf, relbf, Rtab);
    scores_kernel<<<NB, 512, 0, stream>>>(
        r_space, e_space, amask, entbf, Rtab, X2, dist, entr);
}

// Round 8
// 228.150 us; speedup vs baseline: 1.0289x; 1.0289x over previous
//
#include <hip/hip_runtime.h>
#include <math.h>

#define NB   1024
#define NACT 256
#define DIM  256
#define HDIM 512
#define ADIM 512
#define KTOT 1024
#define NE   100000
#define NR   400
#define NRP  448            // NR padded to 64

typedef __attribute__((ext_vector_type(8))) short bf16x8;
typedef __attribute__((ext_vector_type(4))) float f32x4;

__device__ __forceinline__ unsigned short f2bf(float f) {
    unsigned int u = __float_as_uint(f);
    u += 0x7FFF + ((u >> 16) & 1);
    return (unsigned short)(u >> 16);
}
__device__ __forceinline__ float bf2f(unsigned short u) {
    return __uint_as_float(((unsigned int)u) << 16);
}
__device__ __forceinline__ ushort4 cvt4(float4 v) {
    ushort4 o = {f2bf(v.x), f2bf(v.y), f2bf(v.z), f2bf(v.w)};
    return o;
}

// ---------------- prep: z=0 W1T, z=1 W2T (fp32->bf16 transposed), z=2 relbf ----------------
__global__ __launch_bounds__(256) void prep_transpose(
    const float* __restrict__ W1, const float* __restrict__ W2,
    const float* __restrict__ rel,
    ushort* __restrict__ W1T, ushort* __restrict__ W2T,
    ushort* __restrict__ relbf)
{
    const int z = blockIdx.z;
    const int tid = threadIdx.x;
    if (z == 2) {
        // rel fp32 -> bf16 row-major copy: 400*256 = 25600 float4
        const int flat = blockIdx.x * 8 + blockIdx.y;     // 0..127
        const int j = flat * 200 + tid;
        if (tid < 200)
            ((ushort4*)relbf)[j] = cvt4(((const float4*)rel)[j]);
        return;
    }
    __shared__ float t[64][68];
    if (z && blockIdx.x >= 8) return;                 // W2 has K=512
    const int Kd = z ? 512 : 1024;
    const float* in = z ? W2 : W1;
    ushort* out = z ? W2T : W1T;
    const int k0 = blockIdx.x * 64, n0 = blockIdx.y * 64;
    const int kr = tid >> 2, c = tid & 3;
    #pragma unroll
    for (int j = 0; j < 4; ++j) {
        const float4 v = *(const float4*)(in + (size_t)(k0 + kr) * ADIM + n0 + c * 16 + j * 4);
        *(float4*)&t[kr][c * 16 + j * 4] = v;
    }
    __syncthreads();
    const int nr = tid >> 2;
    ushort tmp[16];
    #pragma unroll
    for (int kk = 0; kk < 16; ++kk) tmp[kk] = f2bf(t[c * 16 + kk][nr]);
    *(uint4*)(out + (size_t)(n0 + nr) * Kd + k0 + c * 16)     = *(uint4*)&tmp[0];
    *(uint4*)(out + (size_t)(n0 + nr) * Kd + k0 + c * 16 + 8) = *(uint4*)&tmp[8];
}

// ---------------- gemm1: Hbf = relu_bf16(gather[E|H|Q] @ W1T^T + b1) ----------------
__global__ __launch_bounds__(256) void gemm1_mfma(
    const float* __restrict__ ent, const float* __restrict__ rel,
    const float* __restrict__ hstate,
    const int* __restrict__ e, const int* __restrict__ q,
    const ushort* __restrict__ W1T, const float* __restrict__ b1,
    ushort* __restrict__ Hbf)
{
    const int tid = threadIdx.x;
    __shared__ __align__(16) ushort Als[64][40];   // 32 k + 8 pad -> 80 B rows
    __shared__ __align__(16) ushort Bls[64][40];

    const int g  = blockIdx.x;                        // 0..127
    const int n0 = (g & 7) * 64;
    const int m0 = (g >> 3) * 64;
    const int wave = tid >> 6, lane = tid & 63;
    const int qq   = lane >> 4, l15 = lane & 15;
    const int sm   = tid >> 2, sc = tid & 3;
    const int kofs = sc * 8;

    const int row   = m0 + sm;
    const float* rowE = ent + (size_t)e[row] * DIM;
    const float* rowH = hstate + (size_t)row * HDIM - DIM;
    const float* rowQ = rel + (size_t)q[row] * DIM - (DIM + HDIM);
    const uint4* gb = (const uint4*)(W1T + (size_t)(n0 + sm) * KTOT) + sc;

    f32x4 acc[4];
    #pragma unroll
    for (int mt = 0; mt < 4; ++mt) acc[mt] = (f32x4){0.f, 0.f, 0.f, 0.f};

    float4 pa0 = *(const float4*)(rowE + kofs);
    float4 pa1 = *(const float4*)(rowE + kofs + 4);
    uint4  pb  = gb[0];

    for (int it = 0; it < KTOT / 32; ++it) {
        ushort t8[8];
        t8[0] = f2bf(pa0.x); t8[1] = f2bf(pa0.y); t8[2] = f2bf(pa0.z); t8[3] = f2bf(pa0.w);
        t8[4] = f2bf(pa1.x); t8[5] = f2bf(pa1.y); t8[6] = f2bf(pa1.z); t8[7] = f2bf(pa1.w);
        *(uint4*)&Als[sm][sc * 8] = *(uint4*)t8;
        *(uint4*)&Bls[sm][sc * 8] = pb;
        __syncthreads();
        if (it + 1 < KTOT / 32) {
            const int kg = (it + 1) * 32 + kofs;
            const float* src = (kg < DIM) ? rowE : ((kg < DIM + HDIM) ? rowH : rowQ);
            pa0 = *(const float4*)(src + kg);
            pa1 = *(const float4*)(src + kg + 4);
            pb  = gb[(it + 1) * 4];
        }
        const bf16x8 bfrag = *(const bf16x8*)&Bls[wave * 16 + l15][qq * 8];
        #pragma unroll
        for (int mt = 0; mt < 4; ++mt) {
            const bf16x8 afrag = *(const bf16x8*)&Als[mt * 16 + l15][qq * 8];
            acc[mt] = __builtin_amdgcn_mfma_f32_16x16x32_bf16(afrag, bfrag, acc[mt], 0, 0, 0);
        }
        __syncthreads();
    }
    const int n = n0 + wave * 16 + l15;
    const float bv = b1[n];
    #pragma unroll
    for (int mt = 0; mt < 4; ++mt)
        #pragma unroll
        for (int r = 0; r < 4; ++r) {
            const int m = m0 + mt * 16 + qq * 4 + r;
            Hbf[(size_t)m * ADIM + n] = f2bf(fmaxf(acc[mt][r] + bv, 0.0f));
        }
}

// ------- gemm2: cols<256 -> X2rbf (bf16); cols>=256 -> X2up (fp32) -------
__global__ __launch_bounds__(256) void gemm2_mfma(
    const ushort* __restrict__ A, const ushort* __restrict__ Bt,
    const float* __restrict__ bias, float* __restrict__ X2up,
    ushort* __restrict__ X2rbf)
{
    __shared__ __align__(16) ushort Als[64][40];
    __shared__ __align__(16) ushort Bls[64][40];
    const int tid  = threadIdx.x;
    const int n0   = blockIdx.x * 64;
    const int m0   = blockIdx.y * 64;
    const int wave = tid >> 6, lane = tid & 63;
    const int qq   = lane >> 4, l15 = lane & 15;
    const int sm   = tid >> 2, sc = tid & 3;

    const uint4* ga = (const uint4*)(A  + (size_t)(m0 + sm) * ADIM) + sc;
    const uint4* gb = (const uint4*)(Bt + (size_t)(n0 + sm) * ADIM) + sc;

    f32x4 acc[4];
    #pragma unroll
    for (int mt = 0; mt < 4; ++mt) acc[mt] = (f32x4){0.f, 0.f, 0.f, 0.f};

    uint4 pa = ga[0], pb = gb[0];
    for (int it = 0; it < ADIM / 32; ++it) {
        *(uint4*)&Als[sm][sc * 8] = pa;
        *(uint4*)&Bls[sm][sc * 8] = pb;
        __syncthreads();
        if (it + 1 < ADIM / 32) {
            pa = ga[(it + 1) * 4];
            pb = gb[(it + 1) * 4];
        }
        const bf16x8 bfrag = *(const bf16x8*)&Bls[wave * 16 + l15][qq * 8];
        #pragma unroll
        for (int mt = 0; mt < 4; ++mt) {
            const bf16x8 afrag = *(const bf16x8*)&Als[mt * 16 + l15][qq * 8];
            acc[mt] = __builtin_amdgcn_mfma_f32_16x16x32_bf16(afrag, bfrag, acc[mt], 0, 0, 0);
        }
        __syncthreads();
    }
    const int n = n0 + wave * 16 + l15;
    const float bv = bias[n];
    #pragma unroll
    for (int mt = 0; mt < 4; ++mt)
        #pragma unroll
        for (int r = 0; r < 4; ++r) {
            const int m = m0 + mt * 16 + qq * 4 + r;
            const float v = acc[mt][r] + bv;
            if (n < 256) X2rbf[(size_t)m * DIM + n] = f2bf(v);
            else         X2up [(size_t)m * DIM + (n - 256)] = v;
        }
}

// ------- gemm_rel: R[b][j] = X2rbf[b,:] . relbf[j,:] (fp32, N=400 pad 448) -------
__global__ __launch_bounds__(256) void gemm_rel(
    const ushort* __restrict__ A, const ushort* __restrict__ Bt,
    float* __restrict__ R)
{
    __shared__ __align__(16) ushort Als[64][40];
    __shared__ __align__(16) ushort Bls[64][40];
    const int tid  = threadIdx.x;
    const int n0   = blockIdx.x * 64;
    const int m0   = blockIdx.y * 64;
    const int wave = tid >> 6, lane = tid & 63;
    const int qq   = lane >> 4, l15 = lane & 15;
    const int sm   = tid >> 2, sc = tid & 3;

    const int brow = (n0 + sm < NR) ? (n0 + sm) : (NR - 1);
    const uint4* ga = (const uint4*)(A  + (size_t)(m0 + sm) * DIM) + sc;
    const uint4* gb = (const uint4*)(Bt + (size_t)brow * DIM) + sc;

    f32x4 acc[4];
    #pragma unroll
    for (int mt = 0; mt < 4; ++mt) acc[mt] = (f32x4){0.f, 0.f, 0.f, 0.f};

    uint4 pa = ga[0], pb = gb[0];
    for (int it = 0; it < DIM / 32; ++it) {
        *(uint4*)&Als[sm][sc * 8] = pa;
        *(uint4*)&Bls[sm][sc * 8] = pb;
        __syncthreads();
        if (it + 1 < DIM / 32) {
            pa = ga[(it + 1) * 4];
            pb = gb[(it + 1) * 4];
        }
        const bf16x8 bfrag = *(const bf16x8*)&Bls[wave * 16 + l15][qq * 8];
        #pragma unroll
        for (int mt = 0; mt < 4; ++mt) {
            const bf16x8 afrag = *(const bf16x8*)&Als[mt * 16 + l15][qq * 8];
            acc[mt] = __builtin_amdgcn_mfma_f32_16x16x32_bf16(afrag, bfrag, acc[mt], 0, 0, 0);
        }
        __syncthreads();
    }
    const int n = n0 + wave * 16 + l15;
    if (n < NR) {
        #pragma unroll
        for (int mt = 0; mt < 4; ++mt)
            #pragma unroll
            for (int r = 0; r < 4; ++r) {
                const int m = m0 + mt * 16 + qq * 4 + r;
                R[(size_t)m * NRP + n] = acc[mt][r];
            }
    }
}

// ------- scores: fp32 ent gather + R lookup + masked softmax + entropy -------
__global__ __launch_bounds__(512) void scores_kernel(
    const int* __restrict__ r_space, const int* __restrict__ e_space,
    const float* __restrict__ amask,
    const float* __restrict__ ent, const float* __restrict__ R,
    const float* __restrict__ X2up,
    float* __restrict__ dist_out, float* __restrict__ ent_out)
{
    const int b    = blockIdx.x;
    const int tid  = threadIdx.x;
    const int wave = tid >> 6;
    const int lane = tid & 63;

    __shared__ float xs[DIM];        // X2 upper half only
    __shared__ float sc[NACT];
    __shared__ int   ridx[NACT];
    __shared__ int   eidx[NACT];
    __shared__ float red1[8], red2[8], red3[8];

    if (tid < NACT) ridx[tid] = r_space[(size_t)b * NACT + tid];
    else            eidx[tid - NACT] = e_space[(size_t)b * NACT + tid - NACT];
    if (tid < DIM / 4)
        ((float4*)xs)[tid] = ((const float4*)(X2up + (size_t)b * DIM))[tid];
    __syncthreads();

    const float4 xe = ((const float4*)xs)[lane];
    const float* R_row = R + (size_t)b * NRP;

    const int abase = wave * 32;
    for (int a0 = abase; a0 < abase + 32; a0 += 16) {
        const float rsc = (lane < 16) ? R_row[ridx[a0 + lane]] : 0.0f;
        float4 ev[16];
        #pragma unroll
        for (int i = 0; i < 16; ++i)
            ev[i] = ((const float4*)(ent + (size_t)eidx[a0 + i] * DIM))[lane];
        float p[16];
        #pragma unroll
        for (int i = 0; i < 16; ++i)
            p[i] = ev[i].x * xe.x + ev[i].y * xe.y + ev[i].z * xe.z + ev[i].w * xe.w;
        #pragma unroll
        for (int off = 32; off; off >>= 1) {
            #pragma unroll
            for (int i = 0; i < 16; ++i) p[i] += __shfl_xor(p[i], off);
        }
        float out = p[0];
        #pragma unroll
        for (int i = 1; i < 16; ++i) out = (lane == i) ? p[i] : out;
        if (lane < 16) sc[a0 + lane] = out + rsc;
    }
    __syncthreads();

    float s = -3.0e38f;
    if (tid < NACT) {
        const float m = amask[(size_t)b * NACT + tid];
        s = sc[tid] - (1.0f - m) * 1e31f;
    }

    float mx = s;
    #pragma unroll
    for (int off = 32; off; off >>= 1) mx = fmaxf(mx, __shfl_xor(mx, off));
    if (lane == 0) red1[wave] = mx;
    __syncthreads();
    mx = red1[0];
    #pragma unroll
    for (int w = 1; w < 8; ++w) mx = fmaxf(mx, red1[w]);

    const float ex = (tid < NACT) ? expf(s - mx) : 0.0f;
    float sum = ex;
    #pragma unroll
    for (int off = 32; off; off >>= 1) sum += __shfl_xor(sum, off);
    if (lane == 0) red2[wave] = sum;
    __syncthreads();
    sum = ((red2[0] + red2[1]) + (red2[2] + red2[3]))
        + ((red2[4] + red2[5]) + (red2[6] + red2[7]));

    const float d = ex / sum;
    if (tid < NACT) dist_out[(size_t)b * NACT + tid] = d;

    float t = (tid < NACT) ? d * logf(fmaxf(d, 1e-20f)) : 0.0f;
    #pragma unroll
    for (int off = 32; off; off >>= 1) t += __shfl_xor(t, off);
    if (lane == 0) red3[wave] = t;
    __syncthreads();
    if (tid == 0)
        ent_out[b] = -(((red3[0] + red3[1]) + (red3[2] + red3[3]))
                     + ((red3[4] + red3[5]) + (red3[6] + red3[7])));
}

extern "C" void kernel_launch(void* const* d_in, const int* in_sizes, int n_in,
                              void* d_out, int out_size, void* d_ws, size_t ws_size,
                              hipStream_t stream) {
    const int*   e       = (const int*)d_in[0];
    const int*   q       = (const int*)d_in[1];
    const float* hstate  = (const float*)d_in[2];
    const int*   r_space = (const int*)d_in[3];
    const int*   e_space = (const int*)d_in[4];
    const float* amask   = (const float*)d_in[5];
    const float* ent     = (const float*)d_in[6];
    const float* rel     = (const float*)d_in[7];
    const float* W1      = (const float*)d_in[8];
    const float* b1      = (const float*)d_in[9];
    const float* W2      = (const float*)d_in[10];
    const float* b2      = (const float*)d_in[11];

    ushort* W1T   = (ushort*)d_ws;                       // 512*1024
    ushort* W2T   = W1T   + (size_t)ADIM * KTOT;         // 512*512
    ushort* Hbf   = W2T   + (size_t)ADIM * ADIM;         // 1024*512
    ushort* relbf = Hbf   + (size_t)NB * ADIM;           // 400*256
    ushort* X2rbf = relbf + (size_t)NR * DIM;            // 1024*256
    float*  X2up  = (float*)(X2rbf + (size_t)NB * DIM);  // 1024*256 f32
    float*  Rtab  = X2up + (size_t)NB * DIM;             // 1024*448 f32
    float*  dist  = (float*)d_out;
    float*  entr  = dist + (size_t)NB * NACT;

    prep_transpose<<<dim3(16, 8, 3), 256, 0, stream>>>(W1, W2, rel, W1T, W2T, relbf);
    gemm1_mfma<<<128, 256, 0, stream>>>(ent, rel, hstate, e, q, W1T, b1, Hbf);
    gemm2_mfma<<<dim3(ADIM / 64, NB / 64), 256, 0, stream>>>(Hbf, W2T, b2, X2up, X2rbf);
    gemm_rel<<<dim3(NRP / 64, NB / 64), 256, 0, stream>>>(X2rbf, relbf, Rtab);
    scores_kernel<<<NB, 512, 0, stream>>>(
        r_space, e_space, amask, ent, Rtab, X2up, dist, entr);
}

// Round 9
// 223.040 us; speedup vs baseline: 1.0525x; 1.0229x over previous
//
#include <hip/hip_runtime.h>
#include <math.h>

#define NB   1024
#define NACT 256
#define DIM  256
#define HDIM 512
#define ADIM 512
#define KTOT 1024
#define NE   100000
#define NR   400
#define NRP  448
#define NCAT 704            // 256 (X2 upper half) + 448 (Mtab rows)

typedef __attribute__((ext_vector_type(8))) short bf16x8;
typedef __attribute__((ext_vector_type(4))) float f32x4;

__device__ __forceinline__ unsigned short f2bf(float f) {
    unsigned int u = __float_as_uint(f);
    u += 0x7FFF + ((u >> 16) & 1);
    return (unsigned short)(u >> 16);
}
__device__ __forceinline__ ushort4 cvt4(float4 v) {
    ushort4 o = {f2bf(v.x), f2bf(v.y), f2bf(v.z), f2bf(v.w)};
    return o;
}

// ---------------- prep: W1T, Bcat[0:256)=W2T_upper, W2lowbf, relbf, cvec ----------------
// blocks [0,128): W1T transpose; [128,160): W2T upper -> Bcat; [160,288): W2lowbf;
// [288,388): relbf; [388,390): cvec[r] = rel[r] . b2[0:256)
__global__ __launch_bounds__(256) void prep_kernel(
    const float* __restrict__ W1, const float* __restrict__ W2,
    const float* __restrict__ rel, const float* __restrict__ b2,
    ushort* __restrict__ W1T, ushort* __restrict__ Bcat,
    ushort* __restrict__ W2lowbf, ushort* __restrict__ relbf,
    float* __restrict__ cvec)
{
    const int blk = blockIdx.x, tid = threadIdx.x;
    if (blk < 160) {
        // transpose fp32 [K][512] -> bf16 [n][K]
        __shared__ float t[64][68];
        const float* in; ushort* out; int Kd, k0, n0, rowbase;
        if (blk < 128) {                  // W1: K=1024, 16 k-tiles x 8 n-tiles
            in = W1; out = W1T; Kd = 1024;
            k0 = (blk >> 3) * 64; n0 = (blk & 7) * 64; rowbase = n0;
        } else {                          // W2 upper: K=512, 8 k-tiles x 4 n-tiles
            const int l = blk - 128;
            in = W2; out = Bcat; Kd = 512;
            k0 = (l >> 2) * 64; n0 = 256 + (l & 3) * 64; rowbase = n0 - 256;
        }
        const int kr = tid >> 2, c = tid & 3;
        #pragma unroll
        for (int j = 0; j < 4; ++j) {
            const float4 v = *(const float4*)(in + (size_t)(k0 + kr) * ADIM + n0 + c * 16 + j * 4);
            *(float4*)&t[kr][c * 16 + j * 4] = v;
        }
        __syncthreads();
        const int nr = tid >> 2;
        ushort tmp[16];
        #pragma unroll
        for (int kk = 0; kk < 16; ++kk) tmp[kk] = f2bf(t[c * 16 + kk][nr]);
        *(uint4*)(out + (size_t)(rowbase + nr) * Kd + k0 + c * 16)     = *(uint4*)&tmp[0];
        *(uint4*)(out + (size_t)(rowbase + nr) * Kd + k0 + c * 16 + 8) = *(uint4*)&tmp[8];
    } else if (blk < 288) {
        // W2lowbf[k][d] = bf16(W2[k][d]), d<256 ; 4 rows per block
        const int l = blk - 160;
        const int row = l * 4 + (tid >> 6);
        const int d4  = tid & 63;
        const float4 v = *(const float4*)(W2 + (size_t)row * ADIM + d4 * 4);
        *(ushort4*)(W2lowbf + (size_t)row * DIM + d4 * 4) = cvt4(v);
    } else if (blk < 388) {
        const int j = (blk - 288) * 256 + tid;     // 25600 float4
        ((ushort4*)relbf)[j] = cvt4(((const float4*)rel)[j]);
    } else {
        const int r = (blk - 388) * 256 + tid;
        if (r < NRP) {
            const int rr = (r < NR) ? r : (NR - 1);
            const float* a = rel + (size_t)rr * DIM;
            float s = 0.f;
            for (int d = 0; d < DIM; d += 4) {
                const float4 av = *(const float4*)(a + d);
                const float4 bv = *(const float4*)(b2 + d);
                s += av.x * bv.x + av.y * bv.y + av.z * bv.z + av.w * bv.w;
            }
            cvec[r] = s;
        }
    }
}

// ---------------- mega2: [0,56) gemm_M ; [56,568) gemm1 split-K=4 ----------------
__global__ __launch_bounds__(256) void mega2_kernel(
    const float* __restrict__ ent, const float* __restrict__ rel,
    const float* __restrict__ hstate,
    const int* __restrict__ e, const int* __restrict__ q,
    const ushort* __restrict__ W1T, const ushort* __restrict__ relbf,
    const ushort* __restrict__ W2lowbf,
    ushort* __restrict__ Bcat, float* __restrict__ Hpart)
{
    __shared__ __align__(16) ushort Als[64][40];
    __shared__ __align__(16) ushort Bls[64][40];
    const int blk = blockIdx.x, tid = threadIdx.x;
    const int wave = tid >> 6, lane = tid & 63;
    const int qq   = lane >> 4, l15 = lane & 15;
    const int sm   = tid >> 2, sc = tid & 3;

    f32x4 acc[4];
    #pragma unroll
    for (int mt = 0; mt < 4; ++mt) acc[mt] = (f32x4){0.f, 0.f, 0.f, 0.f};

    if (blk < 56) {
        // ---- gemm_M: Mtab[r][k] = relbf[r,:] . W2lowbf[k,:]  -> Bcat rows 256+r ----
        const int n0 = (blk & 7) * 64;            // k-dim tile
        const int m0 = (blk >> 3) * 64;           // r tile (0..384)
        const int arow = (m0 + sm < NR) ? (m0 + sm) : (NR - 1);
        const uint4* ga = (const uint4*)(relbf + (size_t)arow * DIM) + sc;
        const uint4* gb = (const uint4*)(W2lowbf + (size_t)(n0 + sm) * DIM) + sc;
        uint4 pa = ga[0], pb = gb[0];
        for (int it = 0; it < DIM / 32; ++it) {
            *(uint4*)&Als[sm][sc * 8] = pa;
            *(uint4*)&Bls[sm][sc * 8] = pb;
            __syncthreads();
            if (it + 1 < DIM / 32) { pa = ga[(it + 1) * 4]; pb = gb[(it + 1) * 4]; }
            const bf16x8 bfrag = *(const bf16x8*)&Bls[wave * 16 + l15][qq * 8];
            #pragma unroll
            for (int mt = 0; mt < 4; ++mt) {
                const bf16x8 afrag = *(const bf16x8*)&Als[mt * 16 + l15][qq * 8];
                acc[mt] = __builtin_amdgcn_mfma_f32_16x16x32_bf16(afrag, bfrag, acc[mt], 0, 0, 0);
            }
            __syncthreads();
        }
        const int n = n0 + wave * 16 + l15;
        #pragma unroll
        for (int mt = 0; mt < 4; ++mt)
            #pragma unroll
            for (int r = 0; r < 4; ++r) {
                const int m = m0 + mt * 16 + qq * 4 + r;
                Bcat[(size_t)(256 + m) * ADIM + n] = f2bf(acc[mt][r]);
            }
        return;
    }

    // ---- gemm1 split-K: Hpart[z] = gather[E|H|Q]_chunk @ W1T_chunk^T ----
    const int g  = blk - 56;                      // 0..511
    const int n0 = (g & 7) * 64;
    const int m0 = ((g >> 3) & 15) * 64;
    const int z  = g >> 7;                        // 0..3, k-chunks of 256
    const int kbase = z * 256;
    const int kofs  = sc * 8;

    const int row = m0 + sm;
    const float* abase;
    if (z == 0)      abase = ent + (size_t)e[row] * DIM;
    else if (z == 3) abase = rel + (size_t)q[row] * DIM;
    else             abase = hstate + (size_t)row * HDIM + (kbase - DIM);
    const uint4* gb = (const uint4*)(W1T + (size_t)(n0 + sm) * KTOT + kbase) + sc;

    float4 pa0 = *(const float4*)(abase + kofs);
    float4 pa1 = *(const float4*)(abase + kofs + 4);
    uint4  pb  = gb[0];

    for (int it = 0; it < 8; ++it) {
        ushort t8[8];
        t8[0] = f2bf(pa0.x); t8[1] = f2bf(pa0.y); t8[2] = f2bf(pa0.z); t8[3] = f2bf(pa0.w);
        t8[4] = f2bf(pa1.x); t8[5] = f2bf(pa1.y); t8[6] = f2bf(pa1.z); t8[7] = f2bf(pa1.w);
        *(uint4*)&Als[sm][sc * 8] = *(uint4*)t8;
        *(uint4*)&Bls[sm][sc * 8] = pb;
        __syncthreads();
        if (it + 1 < 8) {
            const int lofs = (it + 1) * 32 + kofs;
            pa0 = *(const float4*)(abase + lofs);
            pa1 = *(const float4*)(abase + lofs + 4);
            pb  = gb[(it + 1) * 4];
        }
        const bf16x8 bfrag = *(const bf16x8*)&Bls[wave * 16 + l15][qq * 8];
        #pragma unroll
        for (int mt = 0; mt < 4; ++mt) {
            const bf16x8 afrag = *(const bf16x8*)&Als[mt * 16 + l15][qq * 8];
            acc[mt] = __builtin_amdgcn_mfma_f32_16x16x32_bf16(afrag, bfrag, acc[mt], 0, 0, 0);
        }
        __syncthreads();
    }
    float* dst = Hpart + (size_t)z * NB * ADIM;
    const int n = n0 + wave * 16 + l15;
    #pragma unroll
    for (int mt = 0; mt < 4; ++mt)
        #pragma unroll
        for (int r = 0; r < 4; ++r) {
            const int m = m0 + mt * 16 + qq * 4 + r;
            dst[(size_t)m * ADIM + n] = acc[mt][r];
        }
}

// ------- gemm2big split-K=2: [X2up | Rtab]_part[z] = relu(sum Hpart + b1)_chunk @ Bcat_chunk^T -------
__global__ __launch_bounds__(256) void gemm2big(
    const float* __restrict__ Hpart, const float* __restrict__ b1,
    const ushort* __restrict__ Bcat, const float* __restrict__ b2,
    const float* __restrict__ cvec,
    float* __restrict__ X2upPart, float* __restrict__ RtabPart)
{
    __shared__ __align__(16) ushort Als[64][40];
    __shared__ __align__(16) ushort Bls[64][40];
    const int tid  = threadIdx.x;
    const int n0   = blockIdx.x * 64;             // 0..640
    const int m0   = blockIdx.y * 64;
    const int z    = blockIdx.z;                  // 0,1 ; k-chunk of 256
    const int kb   = z * 256;
    const int wave = tid >> 6, lane = tid & 63;
    const int qq   = lane >> 4, l15 = lane & 15;
    const int sm   = tid >> 2, sc = tid & 3;

    const size_t arow = (size_t)(m0 + sm) * ADIM + kb;
    const uint4* gbp = (const uint4*)(Bcat + (size_t)(n0 + sm) * ADIM + kb) + sc;

    f32x4 acc[4];
    #pragma unroll
    for (int mt = 0; mt < 4; ++mt) acc[mt] = (f32x4){0.f, 0.f, 0.f, 0.f};

    float4 pz[4][2], pb1[2];
    uint4  pbv;
    {
        const int lk = sc * 8;
        pb1[0] = *(const float4*)(b1 + kb + lk);
        pb1[1] = *(const float4*)(b1 + kb + lk + 4);
        #pragma unroll
        for (int z4 = 0; z4 < 4; ++z4) {
            const float* hp = Hpart + (size_t)z4 * NB * ADIM + arow + lk;
            pz[z4][0] = *(const float4*)hp;
            pz[z4][1] = *(const float4*)(hp + 4);
        }
        pbv = gbp[0];
    }

    for (int it = 0; it < 8; ++it) {
        float4 s0 = pb1[0], s1 = pb1[1];
        #pragma unroll
        for (int z4 = 0; z4 < 4; ++z4) {
            s0.x += pz[z4][0].x; s0.y += pz[z4][0].y; s0.z += pz[z4][0].z; s0.w += pz[z4][0].w;
            s1.x += pz[z4][1].x; s1.y += pz[z4][1].y; s1.z += pz[z4][1].z; s1.w += pz[z4][1].w;
        }
        ushort t8[8];
        t8[0] = f2bf(fmaxf(s0.x, 0.f)); t8[1] = f2bf(fmaxf(s0.y, 0.f));
        t8[2] = f2bf(fmaxf(s0.z, 0.f)); t8[3] = f2bf(fmaxf(s0.w, 0.f));
        t8[4] = f2bf(fmaxf(s1.x, 0.f)); t8[5] = f2bf(fmaxf(s1.y, 0.f));
        t8[6] = f2bf(fmaxf(s1.z, 0.f)); t8[7] = f2bf(fmaxf(s1.w, 0.f));
        *(uint4*)&Als[sm][sc * 8] = *(uint4*)t8;
        *(uint4*)&Bls[sm][sc * 8] = pbv;
        __syncthreads();
        if (it + 1 < 8) {
            const int lk = (it + 1) * 32 + sc * 8;
            pb1[0] = *(const float4*)(b1 + kb + lk);
            pb1[1] = *(const float4*)(b1 + kb + lk + 4);
            #pragma unroll
            for (int z4 = 0; z4 < 4; ++z4) {
                const float* hp = Hpart + (size_t)z4 * NB * ADIM + arow + lk;
                pz[z4][0] = *(const float4*)hp;
                pz[z4][1] = *(const float4*)(hp + 4);
            }
            pbv = gbp[(it + 1) * 4];
        }
        const bf16x8 bfrag = *(const bf16x8*)&Bls[wave * 16 + l15][qq * 8];
        #pragma unroll
        for (int mt = 0; mt < 4; ++mt) {
            const bf16x8 afrag = *(const bf16x8*)&Als[mt * 16 + l15][qq * 8];
            acc[mt] = __builtin_amdgcn_mfma_f32_16x16x32_bf16(afrag, bfrag, acc[mt], 0, 0, 0);
        }
        __syncthreads();
    }
    const int n = n0 + wave * 16 + l15;
    const float extra = (z == 0) ? ((n < 256) ? b2[256 + n] : cvec[n - 256]) : 0.0f;
    #pragma unroll
    for (int mt = 0; mt < 4; ++mt)
        #pragma unroll
        for (int r = 0; r < 4; ++r) {
            const int m = m0 + mt * 16 + qq * 4 + r;
            const float v = acc[mt][r] + extra;
            if (n < 256) X2upPart[(size_t)z * NB * DIM + (size_t)m * DIM + n] = v;
            else         RtabPart[(size_t)z * NB * NRP + (size_t)m * NRP + (n - 256)] = v;
        }
}

// ------- scores: fp32 ent gather + Rtab lookup + masked softmax + entropy -------
__global__ __launch_bounds__(512) void scores_kernel(
    const int* __restrict__ r_space, const int* __restrict__ e_space,
    const float* __restrict__ amask,
    const float* __restrict__ ent,
    const float* __restrict__ RtabPart, const float* __restrict__ X2upPart,
    float* __restrict__ dist_out, float* __restrict__ ent_out)
{
    const int b    = blockIdx.x;
    const int tid  = threadIdx.x;
    const int wave = tid >> 6;
    const int lane = tid & 63;

    __shared__ float xs[DIM];
    __shared__ float sc[NACT];
    __shared__ int   ridx[NACT];
    __shared__ int   eidx[NACT];
    __shared__ float red1[8], red2[8], red3[8];

    if (tid < NACT) ridx[tid] = r_space[(size_t)b * NACT + tid];
    else            eidx[tid - NACT] = e_space[(size_t)b * NACT + tid - NACT];
    if (tid < DIM / 4) {
        float4 v0 = ((const float4*)(X2upPart + (size_t)b * DIM))[tid];
        const float4 v1 = ((const float4*)(X2upPart + (size_t)NB * DIM + (size_t)b * DIM))[tid];
        v0.x += v1.x; v0.y += v1.y; v0.z += v1.z; v0.w += v1.w;
        ((float4*)xs)[tid] = v0;
    }
    __syncthreads();

    const float4 xe = ((const float4*)xs)[lane];
    const float* R0 = RtabPart + (size_t)b * NRP;
    const float* R1 = RtabPart + (size_t)NB * NRP + (size_t)b * NRP;

    const int abase = wave * 32;
    for (int a0 = abase; a0 < abase + 32; a0 += 16) {
        float rsc = 0.0f;
        if (lane < 16) {
            const int ri = ridx[a0 + lane];
            rsc = R0[ri] + R1[ri];
        }
        float4 ev[16];
        #pragma unroll
        for (int i = 0; i < 16; ++i)
            ev[i] = ((const float4*)(ent + (size_t)eidx[a0 + i] * DIM))[lane];
        float p[16];
        #pragma unroll
        for (int i = 0; i < 16; ++i)
            p[i] = ev[i].x * xe.x + ev[i].y * xe.y + ev[i].z * xe.z + ev[i].w * xe.w;
        #pragma unroll
        for (int off = 32; off; off >>= 1) {
            #pragma unroll
            for (int i = 0; i < 16; ++i) p[i] += __shfl_xor(p[i], off);
        }
        float out = p[0];
        #pragma unroll
        for (int i = 1; i < 16; ++i) out = (lane == i) ? p[i] : out;
        if (lane < 16) sc[a0 + lane] = out + rsc;
    }
    __syncthreads();

    float s = -3.0e38f;
    if (tid < NACT) {
        const float m = amask[(size_t)b * NACT + tid];
        s = sc[tid] - (1.0f - m) * 1e31f;
    }

    float mx = s;
    #pragma unroll
    for (int off = 32; off; off >>= 1) mx = fmaxf(mx, __shfl_xor(mx, off));
    if (lane == 0) red1[wave] = mx;
    __syncthreads();
    mx = red1[0];
    #pragma unroll
    for (int w = 1; w < 8; ++w) mx = fmaxf(mx, red1[w]);

    const float ex = (tid < NACT) ? expf(s - mx) : 0.0f;
    float sum = ex;
    #pragma unroll
    for (int off = 32; off; off >>= 1) sum += __shfl_xor(sum, off);
    if (lane == 0) red2[wave] = sum;
    __syncthreads();
    sum = ((red2[0] + red2[1]) + (red2[2] + red2[3]))
        + ((red2[4] + red2[5]) + (red2[6] + red2[7]));

    const float d = ex / sum;
    if (tid < NACT) dist_out[(size_t)b * NACT + tid] = d;

    float t = (tid < NACT) ? d * logf(fmaxf(d, 1e-20f)) : 0.0f;
    #pragma unroll
    for (int off = 32; off; off >>= 1) t += __shfl_xor(t, off);
    if (lane == 0) red3[wave] = t;
    __syncthreads();
    if (tid == 0)
        ent_out[b] = -(((red3[0] + red3[1]) + (red3[2] + red3[3]))
                     + ((red3[4] + red3[5]) + (red3[6] + red3[7])));
}

extern "C" void kernel_launch(void* const* d_in, const int* in_sizes, int n_in,
                              void* d_out, int out_size, void* d_ws, size_t ws_size,
                              hipStream_t stream) {
    const int*   e       = (const int*)d_in[0];
    const int*   q       = (const int*)d_in[1];
    const float* hstate  = (const float*)d_in[2];
    const int*   r_space = (const int*)d_in[3];
    const int*   e_space = (const int*)d_in[4];
    const float* amask   = (const float*)d_in[5];
    const float* ent     = (const float*)d_in[6];
    const float* rel     = (const float*)d_in[7];
    const float* W1      = (const float*)d_in[8];
    const float* b1      = (const float*)d_in[9];
    const float* W2      = (const float*)d_in[10];
    const float* b2      = (const float*)d_in[11];

    ushort* W1T    = (ushort*)d_ws;                      // 512*1024
    ushort* Bcat   = W1T    + (size_t)ADIM * KTOT;       // 704*512
    ushort* W2low  = Bcat   + (size_t)NCAT * ADIM;       // 512*256
    ushort* relbf  = W2low  + (size_t)ADIM * DIM;        // 400*256
    float*  cvec   = (float*)(relbf + (size_t)NR * DIM); // 448
    float*  Hpart  = cvec   + NRP;                       // 4*1024*512
    float*  X2upP  = Hpart  + (size_t)4 * NB * ADIM;     // 2*1024*256
    float*  RtabP  = X2upP  + (size_t)2 * NB * DIM;      // 2*1024*448
    float*  dist   = (float*)d_out;
    float*  entr   = dist + (size_t)NB * NACT;

    prep_kernel<<<390, 256, 0, stream>>>(W1, W2, rel, b2, W1T, Bcat, W2low, relbf, cvec);
    mega2_kernel<<<568, 256, 0, stream>>>(ent, rel, hstate, e, q, W1T, relbf, W2low, Bcat, Hpart);
    gemm2big<<<dim3(11, 16, 2), 256, 0, stream>>>(Hpart, b1, Bcat, b2, cvec, X2upP, RtabP);
    scores_kernel<<<NB, 512, 0, stream>>>(
        r_space, e_space, amask, ent, RtabP, X2upP, dist, entr);
}